// Round 2
// baseline (22622.691 us; speedup 1.0000x reference)
//
#include <hip/hip_runtime.h>
#include <math.h>

#define S_ 4096
#define D_ 512
#define NH_ 8
#define HD_ 64
#define F_ 2048
#define L_ 4
#define C_ 6

// ---------------- RoPE tables: cos/sin[S][HD] ----------------
__global__ void rope_table_k(float* __restrict__ ct, float* __restrict__ st) {
    int i = blockIdx.x * 256 + threadIdx.x;
    if (i >= S_ * HD_) return;
    int pos = i >> 6, j = i & 63;
    float ex = (float)(j & 31) / 32.0f;          // arange(0,HD,2)/HD = (j&31)*2/64
    float inv = 1.0f / powf(10000.0f, ex);
    float f = (float)pos * inv;
    ct[i] = cosf(f);
    st[i] = sinf(f);
}

// ---------------- Encoder: h[s,d] = x[s,:6] @ W_enc + b ----------------
__global__ void encoder_k(const float* __restrict__ x, const float* __restrict__ W,
                          const float* __restrict__ b, float* __restrict__ h) {
    int i = blockIdx.x * 256 + threadIdx.x;
    if (i >= S_ * D_) return;
    int s = i >> 9, d = i & 511;
    float acc = b[d];
#pragma unroll
    for (int c = 0; c < C_; ++c) acc = fmaf(x[s * C_ + c], W[c * D_ + d], acc);
    h[i] = acc;
}

// ---------------- RMSNorm: one block (256 thr) per row of 512 ----------------
__global__ __launch_bounds__(256) void rmsnorm_k(const float* __restrict__ src,
                                                 const float* __restrict__ w,
                                                 float* __restrict__ dst) {
    int s = blockIdx.x;
    int t = threadIdx.x;
    const float* row = src + s * D_;
    float v0 = row[t], v1 = row[t + 256];
    float ss = v0 * v0 + v1 * v1;
#pragma unroll
    for (int m = 32; m >= 1; m >>= 1) ss += __shfl_xor(ss, m);
    __shared__ float red[4];
    if ((t & 63) == 0) red[t >> 6] = ss;
    __syncthreads();
    float tot = red[0] + red[1] + red[2] + red[3];
    float r = rsqrtf(tot * (1.0f / (float)D_) + 1e-5f);
    dst[s * D_ + t] = v0 * r * w[t];
    dst[s * D_ + t + 256] = v1 * r * w[t + 256];
}

// ---------------- fp32 GEMM: C = A(MxK) @ B(KxN) [+C if RESID] ----------------
// 64x64 block tile, BK=16, 256 threads, 4x4 per-thread micro-tile.
template <int RESID>
__global__ __launch_bounds__(256) void gemm_k(const float* __restrict__ A,
                                              const float* __restrict__ B,
                                              float* __restrict__ Cb,
                                              int M, int N, int K) {
    __shared__ float As[16][64];   // [k][m]
    __shared__ float Bs[16][64];   // [k][n]
    int tid = threadIdx.x;
    int row0 = blockIdx.y * 64, col0 = blockIdx.x * 64;
    int tx = tid & 15, ty = tid >> 4;
    float acc[4][4] = {};
    int ak = tid & 15, am = tid >> 4;   // A-load: k = ak, m = am + p*16
    int bn = tid & 63, bk = tid >> 6;   // B-load: n = bn, k = bk + p*4
    const float* Ap = A + (size_t)(row0 + am) * K + ak;
    const float* Bp = B + (size_t)bk * N + col0 + bn;
    for (int k0 = 0; k0 < K; k0 += 16) {
#pragma unroll
        for (int p = 0; p < 4; ++p) As[ak][am + p * 16] = Ap[(size_t)(p * 16) * K + k0];
#pragma unroll
        for (int p = 0; p < 4; ++p) Bs[bk + p * 4][bn] = Bp[(size_t)(k0 + p * 4) * N];
        __syncthreads();
#pragma unroll
        for (int k = 0; k < 16; ++k) {
            float4 av = *(const float4*)&As[k][ty * 4];
            float4 bv = *(const float4*)&Bs[k][tx * 4];
            float ar[4] = {av.x, av.y, av.z, av.w};
            float br[4] = {bv.x, bv.y, bv.z, bv.w};
#pragma unroll
            for (int i = 0; i < 4; ++i)
#pragma unroll
                for (int j = 0; j < 4; ++j) acc[i][j] = fmaf(ar[i], br[j], acc[i][j]);
        }
        __syncthreads();
    }
#pragma unroll
    for (int i = 0; i < 4; ++i) {
        float* cp = Cb + (size_t)(row0 + ty * 4 + i) * N + col0 + tx * 4;
        if (RESID) {
            cp[0] += acc[i][0];
            cp[1] += acc[i][1];
            cp[2] += acc[i][2];
            cp[3] += acc[i][3];
        } else {
            *(float4*)cp = make_float4(acc[i][0], acc[i][1], acc[i][2], acc[i][3]);
        }
    }
}

// ---------------- RoPE apply (in place, pair handled by one thread) ----------------
__global__ void rope_k(float* __restrict__ q, float* __restrict__ k,
                       const float* __restrict__ ct, const float* __restrict__ st) {
    int i = blockIdx.x * 256 + threadIdx.x;
    if (i >= S_ * NH_ * 32) return;
    int j = i & 31;
    int h = (i >> 5) & 7;
    int s = i >> 8;
    int base = s * D_ + h * HD_ + j;
    float c = ct[s * HD_ + j], sn = st[s * HD_ + j];  // table duplicated at j+32
    float q0 = q[base], q1 = q[base + 32];
    q[base] = q0 * c - q1 * sn;
    q[base + 32] = q1 * c + q0 * sn;
    float k0 = k[base], k1 = k[base + 32];
    k[base] = k0 * c - k1 * sn;
    k[base + 32] = k1 * c + k0 * sn;
}

// ---------------- Attention: 1 wave per (head,row), online softmax ----------------
// Block-causal mask: row s attends keys [0, (s/256+1)*256) — skip the rest.
__global__ __launch_bounds__(256) void attn_k(const float* __restrict__ q,
                                              const float* __restrict__ kk,
                                              const float* __restrict__ vv,
                                              float* __restrict__ o) {
    int gw = (blockIdx.x * 256 + threadIdx.x) >> 6;  // global wave id, 0..S*NH-1
    int lane = threadIdx.x & 63;
    int head = gw & 7;
    int row = gw >> 3;
    int nk = ((row >> 8) + 1) << 8;
    float ql = q[row * D_ + head * HD_ + lane] * 0.125f;  // 1/sqrt(64)
    const float* kp = kk + head * HD_ + lane;
    const float* vp = vv + head * HD_ + lane;
    float m = -3.0e38f, l = 0.0f, acc = 0.0f;
    for (int t = 0; t < nk; ++t) {
        float sc = ql * kp[(size_t)t * D_];
        sc += __shfl_xor(sc, 32);
        sc += __shfl_xor(sc, 16);
        sc += __shfl_xor(sc, 8);
        sc += __shfl_xor(sc, 4);
        sc += __shfl_xor(sc, 2);
        sc += __shfl_xor(sc, 1);
        float mn = fmaxf(m, sc);
        float corr = __expf(m - mn);
        float p = __expf(sc - mn);
        l = l * corr + p;
        acc = acc * corr + p * vp[(size_t)t * D_];
        m = mn;
    }
    o[row * D_ + head * HD_ + lane] = acc / l;
}

// ---------------- SiLU(g) * u ----------------
__global__ void silumul_k(const float* __restrict__ g, const float* __restrict__ u,
                          float* __restrict__ o) {
    int i = blockIdx.x * 256 + threadIdx.x;  // grid sized exactly
    float x = g[i];
    o[i] = x / (1.0f + __expf(-x)) * u[i];
}

// ---------------- Decoder: out[s,c] = a[s,:] @ W_dec[:,c] + b_dec[c] ----------------
__global__ void decode_k(const float* __restrict__ a, const float* __restrict__ W,
                         const float* __restrict__ b, float* __restrict__ out) {
    int i = blockIdx.x * 256 + threadIdx.x;
    if (i >= S_ * C_) return;
    int s = i / C_, c = i - s * C_;
    float acc = b[c];
    for (int d = 0; d < D_; ++d) acc = fmaf(a[s * D_ + d], W[d * C_ + c], acc);
    out[i] = acc;
}

extern "C" void kernel_launch(void* const* d_in, const int* in_sizes, int n_in,
                              void* d_out, int out_size, void* d_ws, size_t ws_size,
                              hipStream_t stream) {
    const float* x = (const float*)d_in[0];
    const float* W_enc = (const float*)d_in[1];
    const float* b_enc = (const float*)d_in[2];
    const float* Wq = (const float*)d_in[3];
    const float* Wk = (const float*)d_in[4];
    const float* Wv = (const float*)d_in[5];
    const float* Wo = (const float*)d_in[6];
    const float* Wg = (const float*)d_in[7];
    const float* Wu = (const float*)d_in[8];
    const float* Wd = (const float*)d_in[9];
    const float* ln1 = (const float*)d_in[10];
    const float* ln2 = (const float*)d_in[11];
    const float* ln_f = (const float*)d_in[12];
    const float* W_dec = (const float*)d_in[13];
    const float* b_dec = (const float*)d_in[14];
    float* out = (float*)d_out;

    float* ws = (float*)d_ws;
    float* h = ws;                  // S*D
    float* a = h + S_ * D_;         // S*D
    float* qb = a + S_ * D_;        // S*D
    float* kb = qb + S_ * D_;       // S*D
    float* vb = kb + S_ * D_;       // S*D
    float* ob = vb + S_ * D_;       // S*D
    float* g = qb;                  // alias q..o region: 4*S*D == S*F
    float* u = ob + S_ * D_;        // S*F
    float* ct = u + S_ * F_;        // S*HD
    float* st2 = ct + S_ * HD_;     // S*HD
    // total: 6*S*D + S*F + 2*S*HD floats = ~86 MB

    rope_table_k<<<S_ * HD_ / 256, 256, 0, stream>>>(ct, st2);
    encoder_k<<<S_ * D_ / 256, 256, 0, stream>>>(x, W_enc, b_enc, h);

    dim3 g512(D_ / 64, S_ / 64);
    dim3 gF(F_ / 64, S_ / 64);
    for (int l = 0; l < L_; ++l) {
        rmsnorm_k<<<S_, 256, 0, stream>>>(h, ln1 + l * D_, a);
        gemm_k<0><<<g512, 256, 0, stream>>>(a, Wq + (size_t)l * D_ * D_, qb, S_, D_, D_);
        gemm_k<0><<<g512, 256, 0, stream>>>(a, Wk + (size_t)l * D_ * D_, kb, S_, D_, D_);
        gemm_k<0><<<g512, 256, 0, stream>>>(a, Wv + (size_t)l * D_ * D_, vb, S_, D_, D_);
        rope_k<<<S_ * NH_ * 32 / 256, 256, 0, stream>>>(qb, kb, ct, st2);
        attn_k<<<S_ * NH_ / 4, 256, 0, stream>>>(qb, kb, vb, ob);
        gemm_k<1><<<g512, 256, 0, stream>>>(ob, Wo + (size_t)l * D_ * D_, h, S_, D_, D_);
        rmsnorm_k<<<S_, 256, 0, stream>>>(h, ln2 + l * D_, a);
        gemm_k<0><<<gF, 256, 0, stream>>>(a, Wg + (size_t)l * D_ * F_, g, S_, F_, D_);
        gemm_k<0><<<gF, 256, 0, stream>>>(a, Wu + (size_t)l * D_ * F_, u, S_, F_, D_);
        silumul_k<<<S_ * F_ / 256, 256, 0, stream>>>(g, u, g);
        gemm_k<1><<<g512, 256, 0, stream>>>(g, Wd + (size_t)l * F_ * D_, h, S_, D_, F_);
    }
    rmsnorm_k<<<S_, 256, 0, stream>>>(h, ln_f, a);
    decode_k<<<(S_ * C_ + 255) / 256, 256, 0, stream>>>(a, W_dec, b_dec, out);
}

// Round 4
// 5845.340 us; speedup vs baseline: 3.8702x; 3.8702x over previous
//
#include <hip/hip_runtime.h>
#include <math.h>

#define S_ 4096
#define D_ 512
#define NH_ 8
#define HD_ 64
#define F_ 2048
#define L_ 4
#define C_ 6

// ---------------- RoPE tables: cos/sin[S][HD] ----------------
__global__ void rope_table_k(float* __restrict__ ct, float* __restrict__ st) {
    int i = blockIdx.x * 256 + threadIdx.x;
    if (i >= S_ * HD_) return;
    int pos = i >> 6, j = i & 63;
    float ex = (float)(j & 31) / 32.0f;          // arange(0,HD,2)/HD = (j&31)*2/64
    float inv = 1.0f / powf(10000.0f, ex);
    float f = (float)pos * inv;
    ct[i] = cosf(f);
    st[i] = sinf(f);
}

// ---------------- Encoder: h[s,d] = x[s,:6] @ W_enc + b ----------------
__global__ void encoder_k(const float* __restrict__ x, const float* __restrict__ W,
                          const float* __restrict__ b, float* __restrict__ h) {
    int i = blockIdx.x * 256 + threadIdx.x;
    if (i >= S_ * D_) return;
    int s = i >> 9, d = i & 511;
    float acc = b[d];
#pragma unroll
    for (int c = 0; c < C_; ++c) acc = fmaf(x[s * C_ + c], W[c * D_ + d], acc);
    h[i] = acc;
}

// ---------------- RMSNorm: one block (256 thr) per row of 512 ----------------
__global__ __launch_bounds__(256) void rmsnorm_k(const float* __restrict__ src,
                                                 const float* __restrict__ w,
                                                 float* __restrict__ dst) {
    int s = blockIdx.x;
    int t = threadIdx.x;
    const float* row = src + s * D_;
    float v0 = row[t], v1 = row[t + 256];
    float ss = v0 * v0 + v1 * v1;
#pragma unroll
    for (int m = 32; m >= 1; m >>= 1) ss += __shfl_xor(ss, m);
    __shared__ float red[4];
    if ((t & 63) == 0) red[t >> 6] = ss;
    __syncthreads();
    float tot = red[0] + red[1] + red[2] + red[3];
    float r = rsqrtf(tot * (1.0f / (float)D_) + 1e-5f);
    dst[s * D_ + t] = v0 * r * w[t];
    dst[s * D_ + t + 256] = v1 * r * w[t + 256];
}

// ---------------- fp32 GEMM: C = A(MxK) @ B(KxN) [+C if RESID] ----------------
template <int RESID>
__global__ __launch_bounds__(256) void gemm_k(const float* __restrict__ A,
                                              const float* __restrict__ B,
                                              float* __restrict__ Cb,
                                              int M, int N, int K) {
    __shared__ float As[16][64];   // [k][m]
    __shared__ float Bs[16][64];   // [k][n]
    int tid = threadIdx.x;
    int row0 = blockIdx.y * 64, col0 = blockIdx.x * 64;
    int tx = tid & 15, ty = tid >> 4;
    float acc[4][4] = {};
    int ak = tid & 15, am = tid >> 4;
    int bn = tid & 63, bk = tid >> 6;
    const float* Ap = A + (size_t)(row0 + am) * K + ak;
    const float* Bp = B + (size_t)bk * N + col0 + bn;
    for (int k0 = 0; k0 < K; k0 += 16) {
#pragma unroll
        for (int p = 0; p < 4; ++p) As[ak][am + p * 16] = Ap[(size_t)(p * 16) * K + k0];
#pragma unroll
        for (int p = 0; p < 4; ++p) Bs[bk + p * 4][bn] = Bp[(size_t)(k0 + p * 4) * N];
        __syncthreads();
#pragma unroll
        for (int k = 0; k < 16; ++k) {
            float4 av = *(const float4*)&As[k][ty * 4];
            float4 bv = *(const float4*)&Bs[k][tx * 4];
            float ar[4] = {av.x, av.y, av.z, av.w};
            float br[4] = {bv.x, bv.y, bv.z, bv.w};
#pragma unroll
            for (int i = 0; i < 4; ++i)
#pragma unroll
                for (int j = 0; j < 4; ++j) acc[i][j] = fmaf(ar[i], br[j], acc[i][j]);
        }
        __syncthreads();
    }
#pragma unroll
    for (int i = 0; i < 4; ++i) {
        float* cp = Cb + (size_t)(row0 + ty * 4 + i) * N + col0 + tx * 4;
        if (RESID) {
            cp[0] += acc[i][0];
            cp[1] += acc[i][1];
            cp[2] += acc[i][2];
            cp[3] += acc[i][3];
        } else {
            *(float4*)cp = make_float4(acc[i][0], acc[i][1], acc[i][2], acc[i][3]);
        }
    }
}

// ---------------- RoPE apply (in place) ----------------
__global__ void rope_k(float* __restrict__ q, float* __restrict__ k,
                       const float* __restrict__ ct, const float* __restrict__ st) {
    int i = blockIdx.x * 256 + threadIdx.x;
    if (i >= S_ * NH_ * 32) return;
    int j = i & 31;
    int h = (i >> 5) & 7;
    int s = i >> 8;
    int base = s * D_ + h * HD_ + j;
    float c = ct[s * HD_ + j], sn = st[s * HD_ + j];
    float q0 = q[base], q1 = q[base + 32];
    q[base] = q0 * c - q1 * sn;
    q[base + 32] = q1 * c + q0 * sn;
    float k0 = k[base], k1 = k[base + 32];
    k[base] = k0 * c - k1 * sn;
    k[base + 32] = k1 * c + k0 * sn;
}

// ---------------- Attention v2: tiled, 64-keys-per-lane-tile ----------------
// Block = (head, 16 query rows). 4 waves x 4 rows. K-tile + V^T-tile in LDS
// (XOR-swizzled, conflict-free b128). One shfl-reduce per 64 keys per row.
__global__ __launch_bounds__(256) void attn2_k(const float* __restrict__ qg,
                                               const float* __restrict__ kg,
                                               const float* __restrict__ vg,
                                               float* __restrict__ og) {
    __shared__ float Ks[64 * 64];    // K[key][dim], swizzled 16B blocks
    __shared__ float Vt[64 * 64];    // V^T[dim][key], swizzled 16B blocks
    __shared__ float Qs[16][64];     // Q rows (pre-scaled)
    __shared__ float Ps[4][4][64];   // per-wave, per-row P values
    int tid = threadIdx.x;
    int lane = tid & 63, w = tid >> 6;
    int bid = blockIdx.x;
    int head = bid & 7;
    int r0 = (bid >> 3) << 4;             // first row of the 16-row group
    int nk = ((r0 >> 8) + 1) << 8;        // block-causal key horizon
    {   // stage Q (scaled by 1/sqrt(HD))
        int r = tid >> 4, d0 = (tid & 15) << 2;
        float4 qv = *(const float4*)&qg[(size_t)(r0 + r) * D_ + head * HD_ + d0];
        qv.x *= 0.125f; qv.y *= 0.125f; qv.z *= 0.125f; qv.w *= 0.125f;
        *(float4*)&Qs[r][d0] = qv;
    }
    float m[4], l[4], O[4];
#pragma unroll
    for (int r = 0; r < 4; ++r) { m[r] = -3.0e38f; l[r] = 0.0f; O[r] = 0.0f; }
    int myr = w << 2;  // this wave's first row within block

    for (int t0 = 0; t0 < nk; t0 += 64) {
        __syncthreads();
        {   // stage K and V^T, swizzled
            int kq = tid >> 4, dg = tid & 15;
            int d0 = dg << 2;
#pragma unroll
            for (int i = 0; i < 4; ++i) {
                int key = kq + (i << 4);
                size_t goff = (size_t)(t0 + key) * D_ + head * HD_ + d0;
                float4 kv = *(const float4*)&kg[goff];
                *(float4*)&Ks[key * 64 + ((dg ^ (key & 15)) << 2)] = kv;
                float4 vv = *(const float4*)&vg[goff];
                int kb = key >> 2, k3 = key & 3;
                Vt[(d0 + 0) * 64 + ((kb ^ ((d0 + 0) & 15)) << 2) + k3] = vv.x;
                Vt[(d0 + 1) * 64 + ((kb ^ ((d0 + 1) & 15)) << 2) + k3] = vv.y;
                Vt[(d0 + 2) * 64 + ((kb ^ ((d0 + 2) & 15)) << 2) + k3] = vv.z;
                Vt[(d0 + 3) * 64 + ((kb ^ ((d0 + 3) & 15)) << 2) + k3] = vv.w;
            }
        }
        __syncthreads();
        // K-fragment: lane holds K[lane][0:64]; V-fragment: lane holds V[:][lane]
        float4 kf[16], vf[16];
#pragma unroll
        for (int b = 0; b < 16; ++b)
            kf[b] = *(float4*)&Ks[lane * 64 + ((b ^ (lane & 15)) << 2)];
#pragma unroll
        for (int b = 0; b < 16; ++b)
            vf[b] = *(float4*)&Vt[lane * 64 + ((b ^ (lane & 15)) << 2)];
#pragma unroll
        for (int r = 0; r < 4; ++r) {
            int row = myr + r;
            float s = 0.0f;
#pragma unroll
            for (int b = 0; b < 16; ++b) {
                float4 qv = *(float4*)&Qs[row][b << 2];
                s = fmaf(qv.x, kf[b].x, s);
                s = fmaf(qv.y, kf[b].y, s);
                s = fmaf(qv.z, kf[b].z, s);
                s = fmaf(qv.w, kf[b].w, s);
            }
            // wave-wide online softmax for this 64-key tile
            float mt = s;
#pragma unroll
            for (int xm = 32; xm >= 1; xm >>= 1) mt = fmaxf(mt, __shfl_xor(mt, xm));
            float mn = fmaxf(m[r], mt);
            float p = __expf(s - mn);
            float corr = __expf(m[r] - mn);
            m[r] = mn;
            float ps = p;
#pragma unroll
            for (int xm = 32; xm >= 1; xm >>= 1) ps += __shfl_xor(ps, xm);
            l[r] = l[r] * corr + ps;
            Ps[w][r][lane] = p;
            float acc = 0.0f;
#pragma unroll
            for (int b = 0; b < 16; ++b) {
                float4 pv = *(float4*)&Ps[w][r][b << 2];
                acc = fmaf(pv.x, vf[b].x, acc);
                acc = fmaf(pv.y, vf[b].y, acc);
                acc = fmaf(pv.z, vf[b].z, acc);
                acc = fmaf(pv.w, vf[b].w, acc);
            }
            O[r] = O[r] * corr + acc;
        }
    }
#pragma unroll
    for (int r = 0; r < 4; ++r)
        og[(size_t)(r0 + myr + r) * D_ + head * HD_ + lane] = O[r] / l[r];
}

// ---------------- SiLU(g) * u ----------------
__global__ void silumul_k(const float* __restrict__ g, const float* __restrict__ u,
                          float* __restrict__ o) {
    int i = blockIdx.x * 256 + threadIdx.x;
    float x = g[i];
    o[i] = x / (1.0f + __expf(-x)) * u[i];
}

// ---------------- Decoder ----------------
__global__ void decode_k(const float* __restrict__ a, const float* __restrict__ W,
                         const float* __restrict__ b, float* __restrict__ out) {
    int i = blockIdx.x * 256 + threadIdx.x;
    if (i >= S_ * C_) return;
    int s = i / C_, c = i - s * C_;
    float acc = b[c];
    for (int d = 0; d < D_; ++d) acc = fmaf(a[s * D_ + d], W[d * C_ + c], acc);
    out[i] = acc;
}

extern "C" void kernel_launch(void* const* d_in, const int* in_sizes, int n_in,
                              void* d_out, int out_size, void* d_ws, size_t ws_size,
                              hipStream_t stream) {
    const float* x = (const float*)d_in[0];
    const float* W_enc = (const float*)d_in[1];
    const float* b_enc = (const float*)d_in[2];
    const float* Wq = (const float*)d_in[3];
    const float* Wk = (const float*)d_in[4];
    const float* Wv = (const float*)d_in[5];
    const float* Wo = (const float*)d_in[6];
    const float* Wg = (const float*)d_in[7];
    const float* Wu = (const float*)d_in[8];
    const float* Wd = (const float*)d_in[9];
    const float* ln1 = (const float*)d_in[10];
    const float* ln2 = (const float*)d_in[11];
    const float* ln_f = (const float*)d_in[12];
    const float* W_dec = (const float*)d_in[13];
    const float* b_dec = (const float*)d_in[14];
    float* out = (float*)d_out;

    float* ws = (float*)d_ws;
    float* h = ws;                  // S*D
    float* a = h + S_ * D_;         // S*D
    float* qb = a + S_ * D_;        // S*D
    float* kb = qb + S_ * D_;       // S*D
    float* vb = kb + S_ * D_;       // S*D
    float* ob = vb + S_ * D_;       // S*D
    float* g = qb;                  // alias q..o region: 4*S*D == S*F
    float* u = ob + S_ * D_;        // S*F
    float* ct = u + S_ * F_;        // S*HD
    float* st2 = ct + S_ * HD_;     // S*HD

    rope_table_k<<<S_ * HD_ / 256, 256, 0, stream>>>(ct, st2);
    encoder_k<<<S_ * D_ / 256, 256, 0, stream>>>(x, W_enc, b_enc, h);

    dim3 g512(D_ / 64, S_ / 64);
    dim3 gF(F_ / 64, S_ / 64);
    for (int l = 0; l < L_; ++l) {
        rmsnorm_k<<<S_, 256, 0, stream>>>(h, ln1 + l * D_, a);
        gemm_k<0><<<g512, 256, 0, stream>>>(a, Wq + (size_t)l * D_ * D_, qb, S_, D_, D_);
        gemm_k<0><<<g512, 256, 0, stream>>>(a, Wk + (size_t)l * D_ * D_, kb, S_, D_, D_);
        gemm_k<0><<<g512, 256, 0, stream>>>(a, Wv + (size_t)l * D_ * D_, vb, S_, D_, D_);
        rope_k<<<S_ * NH_ * 32 / 256, 256, 0, stream>>>(qb, kb, ct, st2);
        attn2_k<<<(S_ / 16) * NH_, 256, 0, stream>>>(qb, kb, vb, ob);
        gemm_k<1><<<g512, 256, 0, stream>>>(ob, Wo + (size_t)l * D_ * D_, h, S_, D_, D_);
        rmsnorm_k<<<S_, 256, 0, stream>>>(h, ln2 + l * D_, a);
        gemm_k<0><<<gF, 256, 0, stream>>>(a, Wg + (size_t)l * D_ * F_, g, S_, F_, D_);
        gemm_k<0><<<gF, 256, 0, stream>>>(a, Wu + (size_t)l * D_ * F_, u, S_, F_, D_);
        silumul_k<<<S_ * F_ / 256, 256, 0, stream>>>(g, u, g);
        gemm_k<1><<<g512, 256, 0, stream>>>(g, Wd + (size_t)l * F_ * D_, h, S_, D_, F_);
    }
    rmsnorm_k<<<S_, 256, 0, stream>>>(h, ln_f, a);
    decode_k<<<(S_ * C_ + 255) / 256, 256, 0, stream>>>(a, W_dec, b_dec, out);
}

// Round 6
// 3514.905 us; speedup vs baseline: 6.4362x; 1.6630x over previous
//
#include <hip/hip_runtime.h>
#include <math.h>

#define S_ 4096
#define D_ 512
#define NH_ 8
#define HD_ 64
#define F_ 2048
#define L_ 4
#define C_ 6

typedef __attribute__((ext_vector_type(8))) short bf16x8;
typedef __attribute__((ext_vector_type(4))) float f32x4;
typedef unsigned short u16;

__device__ __forceinline__ float bf2f(u16 u) {
    union { unsigned int i; float f; } v; v.i = ((unsigned)u) << 16; return v.f;
}
__device__ __forceinline__ u16 f2bf(float f) {
    union { float f; unsigned int i; } v; v.f = f;
    unsigned r = v.i + 0x7FFF + ((v.i >> 16) & 1);
    return (u16)(r >> 16);
}

// ---------------- RoPE tables ----------------
__global__ void rope_table_k(float* __restrict__ ct, float* __restrict__ st) {
    int i = blockIdx.x * 256 + threadIdx.x;
    if (i >= S_ * HD_) return;
    int pos = i >> 6, j = i & 63;
    float ex = (float)(j & 31) / 32.0f;
    float inv = 1.0f / powf(10000.0f, ex);
    float f = (float)pos * inv;
    ct[i] = cosf(f);
    st[i] = sinf(f);
}

// ---------------- Encoder (fp32 h) ----------------
__global__ void encoder_k(const float* __restrict__ x, const float* __restrict__ W,
                          const float* __restrict__ b, float* __restrict__ h) {
    int i = blockIdx.x * 256 + threadIdx.x;
    if (i >= S_ * D_) return;
    int s = i >> 9, d = i & 511;
    float acc = b[d];
#pragma unroll
    for (int c = 0; c < C_; ++c) acc = fmaf(x[s * C_ + c], W[c * D_ + d], acc);
    h[i] = acc;
}

// ---------------- Weight transpose+bf16: W[K][N] f32 -> Wt[N][K] bf16 ----------------
__global__ __launch_bounds__(256) void conv_t_k(const float* __restrict__ W, u16* __restrict__ Wt,
                                                int K, int N, long wstride, long tstride, long dstoff) {
    __shared__ float t[32][33];
    int l = blockIdx.z;
    const float* Ws = W + (long)l * wstride;
    u16* Wo = Wt + (long)l * tstride + dstoff;
    int kt = blockIdx.y * 32, nt = blockIdx.x * 32;
    int tx = threadIdx.x & 31, ty = threadIdx.x >> 5;
#pragma unroll
    for (int i = 0; i < 4; ++i)
        t[ty + i * 8][tx] = Ws[(size_t)(kt + ty + i * 8) * N + nt + tx];
    __syncthreads();
#pragma unroll
    for (int i = 0; i < 4; ++i)
        Wo[(size_t)(nt + ty + i * 8) * K + kt + tx] = f2bf(t[tx][ty + i * 8]);
}

// ---------------- RMSNorm: fp32 in, bf16 out ----------------
__global__ __launch_bounds__(256) void rmsnorm_k(const float* __restrict__ src,
                                                 const float* __restrict__ w,
                                                 u16* __restrict__ dst) {
    int s = blockIdx.x;
    int t = threadIdx.x;
    const float* row = src + s * D_;
    float v0 = row[t], v1 = row[t + 256];
    float ss = v0 * v0 + v1 * v1;
#pragma unroll
    for (int m = 32; m >= 1; m >>= 1) ss += __shfl_xor(ss, m);
    __shared__ float red[4];
    if ((t & 63) == 0) red[t >> 6] = ss;
    __syncthreads();
    float tot = red[0] + red[1] + red[2] + red[3];
    float r = rsqrtf(tot * (1.0f / (float)D_) + 1e-5f);
    dst[s * D_ + t] = f2bf(v0 * r * w[t]);
    dst[s * D_ + t + 256] = f2bf(v1 * r * w[t + 256]);
}

// ---------------- bf16 MFMA GEMM: C = A[M][K] @ Bt[N][K]^T ----------------
// BM=128 BN=64 BK=32, 256 thr (4 waves, 2x2), wave tile 64x32 (4x2 16x16 frags).
// LDS rows padded to 40 bf16 (80B): 16B-aligned, conflict-light.
template <int RESID>
__global__ __launch_bounds__(256) void mm_k(const u16* __restrict__ A,
                                            const u16* __restrict__ Bt,
                                            void* __restrict__ Cb,
                                            int M, int N, int K) {
    __shared__ u16 As[128][40];
    __shared__ u16 Bs[64][40];
    int tid = threadIdx.x;
    int l = tid & 63, w = tid >> 6;
    int row0 = blockIdx.y * 128, col0 = blockIdx.x * 64;
    int wm = (w >> 1) * 64, wn = (w & 1) * 32;
    f32x4 acc[4][2] = {};
    for (int kk = 0; kk < K; kk += 32) {
        __syncthreads();
#pragma unroll
        for (int it = 0; it < 2; ++it) {   // A: 128 rows x 4 chunks of 8
            int i = tid + it * 256;
            int r = i >> 2, kb = i & 3;
            *(bf16x8*)&As[r][kb * 8] = *(const bf16x8*)&A[(size_t)(row0 + r) * K + kk + kb * 8];
        }
        {   // B: 64 rows x 4 chunks
            int r = tid >> 2, kb = tid & 3;
            *(bf16x8*)&Bs[r][kb * 8] = *(const bf16x8*)&Bt[(size_t)(col0 + r) * K + kk + kb * 8];
        }
        __syncthreads();
        int koff = (l >> 4) * 8;
        bf16x8 af[4], bf[2];
#pragma unroll
        for (int m = 0; m < 4; ++m) af[m] = *(bf16x8*)&As[wm + m * 16 + (l & 15)][koff];
#pragma unroll
        for (int n = 0; n < 2; ++n) bf[n] = *(bf16x8*)&Bs[wn + n * 16 + (l & 15)][koff];
#pragma unroll
        for (int m = 0; m < 4; ++m)
#pragma unroll
            for (int n = 0; n < 2; ++n)
                acc[m][n] = __builtin_amdgcn_mfma_f32_16x16x32_bf16(af[m], bf[n], acc[m][n], 0, 0, 0);
    }
    // C/D: col = l&15, row = 4*(l>>4) + r
    int cg = l & 15, rg = (l >> 4) * 4;
#pragma unroll
    for (int m = 0; m < 4; ++m)
#pragma unroll
        for (int n = 0; n < 2; ++n)
#pragma unroll
            for (int r = 0; r < 4; ++r) {
                int grow = row0 + wm + m * 16 + rg + r;
                int gcol = col0 + wn + n * 16 + cg;
                if (RESID) {
                    ((float*)Cb)[(size_t)grow * N + gcol] += acc[m][n][r];
                } else {
                    ((u16*)Cb)[(size_t)grow * N + gcol] = f2bf(acc[m][n][r]);
                }
            }
}

// ---------------- RoPE apply on fused qkv bf16 (q + k) ----------------
__global__ void rope_k(u16* __restrict__ qkv, const float* __restrict__ ct,
                       const float* __restrict__ st) {
    int i = blockIdx.x * 256 + threadIdx.x;
    if (i >= S_ * NH_ * 32) return;
    int j = i & 31;
    int hh = (i >> 5) & 7;
    int s = i >> 8;
    int base = s * 1536 + hh * HD_ + j;
    float c = ct[s * HD_ + j], sn = st[s * HD_ + j];
    float q0 = bf2f(qkv[base]), q1 = bf2f(qkv[base + 32]);
    qkv[base] = f2bf(q0 * c - q1 * sn);
    qkv[base + 32] = f2bf(q1 * c + q0 * sn);
    float k0 = bf2f(qkv[base + 512]), k1 = bf2f(qkv[base + 512 + 32]);
    qkv[base + 512] = f2bf(k0 * c - k1 * sn);
    qkv[base + 512 + 32] = f2bf(k1 * c + k0 * sn);
}

// ---------------- Attention: tiled fp32 math, bf16 I/O ----------------
// Block = (head, 16 rows), 4 waves x 4 rows. K + V^T staged in LDS, swizzled.
__global__ __launch_bounds__(256) void attn2_k(const u16* __restrict__ qkv,
                                               u16* __restrict__ og) {
    __shared__ float Ks[64 * 64];
    __shared__ float Vt[64 * 64];
    __shared__ float Qs[16][64];
    __shared__ float Ps[4][4][64];
    int tid = threadIdx.x;
    int lane = tid & 63, w = tid >> 6;
    int bid = blockIdx.x;
    int head = bid & 7;
    int r0 = (bid >> 3) << 4;
    int nk = ((r0 >> 8) + 1) << 8;
    {   // stage Q (scaled)
        int r = tid >> 4, d0 = (tid & 15) << 2;
        ushort4 qv = *(const ushort4*)&qkv[(size_t)(r0 + r) * 1536 + head * HD_ + d0];
        Qs[r][d0 + 0] = bf2f(qv.x) * 0.125f;
        Qs[r][d0 + 1] = bf2f(qv.y) * 0.125f;
        Qs[r][d0 + 2] = bf2f(qv.z) * 0.125f;
        Qs[r][d0 + 3] = bf2f(qv.w) * 0.125f;
    }
    float m[4], l[4], O[4];
#pragma unroll
    for (int r = 0; r < 4; ++r) { m[r] = -3.0e38f; l[r] = 0.0f; O[r] = 0.0f; }
    int myr = w << 2;

    for (int t0 = 0; t0 < nk; t0 += 64) {
        __syncthreads();
        {   // stage K[key][dim] swizzled (16B blocks)
            int kq = tid >> 4, dg = tid & 15;
            int d0 = dg << 2;
#pragma unroll
            for (int i = 0; i < 4; ++i) {
                int key = kq + (i << 4);
                ushort4 kv = *(const ushort4*)&qkv[(size_t)(t0 + key) * 1536 + 512 + head * HD_ + d0];
                float4 kf4 = make_float4(bf2f(kv.x), bf2f(kv.y), bf2f(kv.z), bf2f(kv.w));
                *(float4*)&Ks[key * 64 + ((dg ^ (key & 15)) << 2)] = kf4;
            }
        }
        {   // stage V^T[dim][key] swizzled — coalesced per-dim gather
            int dim = tid & 63, kb = tid >> 6;   // kb in 0..3 -> keys kb*16..+15
            float v[16];
#pragma unroll
            for (int j = 0; j < 16; ++j)
                v[j] = bf2f(qkv[(size_t)(t0 + kb * 16 + j) * 1536 + 1024 + head * HD_ + dim]);
#pragma unroll
            for (int q = 0; q < 4; ++q) {
                int slot = kb * 4 + q;
                *(float4*)&Vt[dim * 64 + ((slot ^ (dim & 15)) << 2)] =
                    make_float4(v[4 * q], v[4 * q + 1], v[4 * q + 2], v[4 * q + 3]);
            }
        }
        __syncthreads();
        float4 kf[16], vf[16];
#pragma unroll
        for (int b = 0; b < 16; ++b)
            kf[b] = *(float4*)&Ks[lane * 64 + ((b ^ (lane & 15)) << 2)];
#pragma unroll
        for (int b = 0; b < 16; ++b)
            vf[b] = *(float4*)&Vt[lane * 64 + ((b ^ (lane & 15)) << 2)];
#pragma unroll
        for (int r = 0; r < 4; ++r) {
            int row = myr + r;
            float s = 0.0f;
#pragma unroll
            for (int b = 0; b < 16; ++b) {
                float4 qv = *(float4*)&Qs[row][b << 2];
                s = fmaf(qv.x, kf[b].x, s);
                s = fmaf(qv.y, kf[b].y, s);
                s = fmaf(qv.z, kf[b].z, s);
                s = fmaf(qv.w, kf[b].w, s);
            }
            float mt = s;
#pragma unroll
            for (int xm = 32; xm >= 1; xm >>= 1) mt = fmaxf(mt, __shfl_xor(mt, xm));
            float mn = fmaxf(m[r], mt);
            float p = __expf(s - mn);
            float corr = __expf(m[r] - mn);
            m[r] = mn;
            float ps = p;
#pragma unroll
            for (int xm = 32; xm >= 1; xm >>= 1) ps += __shfl_xor(ps, xm);
            l[r] = l[r] * corr + ps;
            Ps[w][r][lane] = p;
            float acc = 0.0f;
#pragma unroll
            for (int b = 0; b < 16; ++b) {
                float4 pv = *(float4*)&Ps[w][r][b << 2];
                acc = fmaf(pv.x, vf[b].x, acc);
                acc = fmaf(pv.y, vf[b].y, acc);
                acc = fmaf(pv.z, vf[b].z, acc);
                acc = fmaf(pv.w, vf[b].w, acc);
            }
            O[r] = O[r] * corr + acc;
        }
    }
#pragma unroll
    for (int r = 0; r < 4; ++r)
        og[(size_t)(r0 + myr + r) * D_ + head * HD_ + lane] = f2bf(O[r] / l[r]);
}

// ---------------- SiLU(g)*u from fused gu bf16 ----------------
__global__ void silumul_k(const u16* __restrict__ gu, u16* __restrict__ gs) {
    int i = blockIdx.x * 256 + threadIdx.x;   // S*F threads
    int s = i >> 11, f = i & 2047;
    float x = bf2f(gu[(size_t)s * 4096 + f]);
    float u = bf2f(gu[(size_t)s * 4096 + 2048 + f]);
    gs[i] = f2bf(x / (1.0f + __expf(-x)) * u);
}

// ---------------- Decoder (bf16 a, fp32 out) ----------------
__global__ void decode_k(const u16* __restrict__ a, const float* __restrict__ W,
                         const float* __restrict__ b, float* __restrict__ out) {
    int i = blockIdx.x * 256 + threadIdx.x;
    if (i >= S_ * C_) return;
    int s = i / C_, c = i - s * C_;
    float acc = b[c];
    for (int d = 0; d < D_; ++d) acc = fmaf(bf2f(a[s * D_ + d]), W[d * C_ + c], acc);
    out[i] = acc;
}

extern "C" void kernel_launch(void* const* d_in, const int* in_sizes, int n_in,
                              void* d_out, int out_size, void* d_ws, size_t ws_size,
                              hipStream_t stream) {
    const float* x = (const float*)d_in[0];
    const float* W_enc = (const float*)d_in[1];
    const float* b_enc = (const float*)d_in[2];
    const float* Wq = (const float*)d_in[3];
    const float* Wk = (const float*)d_in[4];
    const float* Wv = (const float*)d_in[5];
    const float* Wo = (const float*)d_in[6];
    const float* Wg = (const float*)d_in[7];
    const float* Wu = (const float*)d_in[8];
    const float* Wd = (const float*)d_in[9];
    const float* ln1 = (const float*)d_in[10];
    const float* ln2 = (const float*)d_in[11];
    const float* ln_f = (const float*)d_in[12];
    const float* W_dec = (const float*)d_in[13];
    const float* b_dec = (const float*)d_in[14];
    float* out = (float*)d_out;

    // ---- workspace layout ----
    char* p = (char*)d_ws;
    float* h = (float*)p;          p += (size_t)S_ * D_ * 4;        // 8 MB
    float* ct = (float*)p;         p += (size_t)S_ * HD_ * 4;       // 1 MB
    float* st = (float*)p;         p += (size_t)S_ * HD_ * 4;       // 1 MB
    u16* a_bf = (u16*)p;           p += (size_t)S_ * D_ * 2;        // 4 MB
    u16* qkv = (u16*)p;            p += (size_t)S_ * 1536 * 2;      // 12.6 MB
    u16* ob = (u16*)p;             p += (size_t)S_ * D_ * 2;        // 4 MB
    u16* gu = (u16*)p;             p += (size_t)S_ * 4096 * 2;      // 33.5 MB
    u16* gs = (u16*)p;             p += (size_t)S_ * F_ * 2;        // 16.8 MB
    u16* Wqkv_t = (u16*)p;         p += (size_t)L_ * 1536 * 512 * 2;
    u16* Wo_t = (u16*)p;           p += (size_t)L_ * 512 * 512 * 2;
    u16* Wgu_t = (u16*)p;          p += (size_t)L_ * 4096 * 512 * 2;
    u16* Wd_t = (u16*)p;           p += (size_t)L_ * 512 * 2048 * 2;

    rope_table_k<<<S_ * HD_ / 256, 256, 0, stream>>>(ct, st);
    encoder_k<<<S_ * D_ / 256, 256, 0, stream>>>(x, W_enc, b_enc, h);

    // weight convert+transpose (every call; ws is re-poisoned)
    dim3 c512(16, 16, L_);
    conv_t_k<<<c512, 256, 0, stream>>>(Wq, Wqkv_t, 512, 512, 512L * 512, 1536L * 512, 0);
    conv_t_k<<<c512, 256, 0, stream>>>(Wk, Wqkv_t, 512, 512, 512L * 512, 1536L * 512, 512L * 512);
    conv_t_k<<<c512, 256, 0, stream>>>(Wv, Wqkv_t, 512, 512, 512L * 512, 1536L * 512, 1024L * 512);
    conv_t_k<<<c512, 256, 0, stream>>>(Wo, Wo_t, 512, 512, 512L * 512, 512L * 512, 0);
    dim3 cgu(64, 16, L_);
    conv_t_k<<<cgu, 256, 0, stream>>>(Wg, Wgu_t, 512, 2048, 512L * 2048, 4096L * 512, 0);
    conv_t_k<<<cgu, 256, 0, stream>>>(Wu, Wgu_t, 512, 2048, 512L * 2048, 4096L * 512, 2048L * 512);
    dim3 cwd(16, 64, L_);
    conv_t_k<<<cwd, 256, 0, stream>>>(Wd, Wd_t, 2048, 512, 2048L * 512, 512L * 2048, 0);

    dim3 gqkv(1536 / 64, S_ / 128);
    dim3 ggu(4096 / 64, S_ / 128);
    dim3 g512(512 / 64, S_ / 128);
    for (int l = 0; l < L_; ++l) {
        rmsnorm_k<<<S_, 256, 0, stream>>>(h, ln1 + l * D_, a_bf);
        mm_k<0><<<gqkv, 256, 0, stream>>>(a_bf, Wqkv_t + (size_t)l * 1536 * 512, qkv, S_, 1536, 512);
        rope_k<<<S_ * NH_ * 32 / 256, 256, 0, stream>>>(qkv, ct, st);
        attn2_k<<<(S_ / 16) * NH_, 256, 0, stream>>>(qkv, ob);
        mm_k<1><<<g512, 256, 0, stream>>>(ob, Wo_t + (size_t)l * 512 * 512, h, S_, 512, 512);
        rmsnorm_k<<<S_, 256, 0, stream>>>(h, ln2 + l * D_, a_bf);
        mm_k<0><<<ggu, 256, 0, stream>>>(a_bf, Wgu_t + (size_t)l * 4096 * 512, gu, S_, 4096, 512);
        silumul_k<<<S_ * F_ / 256, 256, 0, stream>>>(gu, gs);
        mm_k<1><<<g512, 256, 0, stream>>>(gs, Wd_t + (size_t)l * 512 * 2048, h, S_, 512, 2048);
    }
    rmsnorm_k<<<S_, 256, 0, stream>>>(h, ln_f, a_bf);
    decode_k<<<(S_ * C_ + 255) / 256, 256, 0, stream>>>(a_bf, W_dec, b_dec, out);
}

// Round 7
// 1157.009 us; speedup vs baseline: 19.5527x; 3.0379x over previous
//
#include <hip/hip_runtime.h>
#include <math.h>

#define S_ 4096
#define D_ 512
#define NH_ 8
#define HD_ 64
#define F_ 2048
#define L_ 4
#define C_ 6

typedef __attribute__((ext_vector_type(8))) short bf16x8;
typedef __attribute__((ext_vector_type(4))) float f32x4;
typedef unsigned short u16;

__device__ __forceinline__ float bf2f(u16 u) {
    union { unsigned int i; float f; } v; v.i = ((unsigned)u) << 16; return v.f;
}
__device__ __forceinline__ u16 f2bf(float f) {
    union { float f; unsigned int i; } v; v.f = f;
    unsigned r = v.i + 0x7FFF + ((v.i >> 16) & 1);
    return (u16)(r >> 16);
}

// ---------------- RoPE tables ----------------
__global__ void rope_table_k(float* __restrict__ ct, float* __restrict__ st) {
    int i = blockIdx.x * 256 + threadIdx.x;
    if (i >= S_ * HD_) return;
    int pos = i >> 6, j = i & 63;
    float ex = (float)(j & 31) / 32.0f;
    float inv = 1.0f / powf(10000.0f, ex);
    float f = (float)pos * inv;
    ct[i] = cosf(f);
    st[i] = sinf(f);
}

// ---------------- Encoder (fp32 h) ----------------
__global__ void encoder_k(const float* __restrict__ x, const float* __restrict__ W,
                          const float* __restrict__ b, float* __restrict__ h) {
    int i = blockIdx.x * 256 + threadIdx.x;
    if (i >= S_ * D_) return;
    int s = i >> 9, d = i & 511;
    float acc = b[d];
#pragma unroll
    for (int c = 0; c < C_; ++c) acc = fmaf(x[s * C_ + c], W[c * D_ + d], acc);
    h[i] = acc;
}

// ---------------- Weight transpose+bf16: W[K][N] f32 -> Wt[N][K] bf16 ----------------
__global__ __launch_bounds__(256) void conv_t_k(const float* __restrict__ W, u16* __restrict__ Wt,
                                                int K, int N, long wstride, long tstride, long dstoff) {
    __shared__ float t[32][33];
    int l = blockIdx.z;
    const float* Ws = W + (long)l * wstride;
    u16* Wo = Wt + (long)l * tstride + dstoff;
    int kt = blockIdx.y * 32, nt = blockIdx.x * 32;
    int tx = threadIdx.x & 31, ty = threadIdx.x >> 5;
#pragma unroll
    for (int i = 0; i < 4; ++i)
        t[ty + i * 8][tx] = Ws[(size_t)(kt + ty + i * 8) * N + nt + tx];
    __syncthreads();
#pragma unroll
    for (int i = 0; i < 4; ++i)
        Wo[(size_t)(nt + ty + i * 8) * K + kt + tx] = f2bf(t[tx][ty + i * 8]);
}

// ---------------- RMSNorm: fp32 in, bf16 out ----------------
__global__ __launch_bounds__(256) void rmsnorm_k(const float* __restrict__ src,
                                                 const float* __restrict__ w,
                                                 u16* __restrict__ dst) {
    int s = blockIdx.x;
    int t = threadIdx.x;
    const float* row = src + s * D_;
    float v0 = row[t], v1 = row[t + 256];
    float ss = v0 * v0 + v1 * v1;
#pragma unroll
    for (int m = 32; m >= 1; m >>= 1) ss += __shfl_xor(ss, m);
    __shared__ float red[4];
    if ((t & 63) == 0) red[t >> 6] = ss;
    __syncthreads();
    float tot = red[0] + red[1] + red[2] + red[3];
    float r = rsqrtf(tot * (1.0f / (float)D_) + 1e-5f);
    dst[s * D_ + t] = f2bf(v0 * r * w[t]);
    dst[s * D_ + t + 256] = f2bf(v1 * r * w[t + 256]);
}

// ---------------- bf16 MFMA GEMM: C = A[M][K] @ Bt[N][K]^T ----------------
template <int RESID>
__global__ __launch_bounds__(256) void mm_k(const u16* __restrict__ A,
                                            const u16* __restrict__ Bt,
                                            void* __restrict__ Cb,
                                            int M, int N, int K) {
    __shared__ u16 As[128][40];
    __shared__ u16 Bs[64][40];
    int tid = threadIdx.x;
    int l = tid & 63, w = tid >> 6;
    int row0 = blockIdx.y * 128, col0 = blockIdx.x * 64;
    int wm = (w >> 1) * 64, wn = (w & 1) * 32;
    f32x4 acc[4][2] = {};
    for (int kk = 0; kk < K; kk += 32) {
        __syncthreads();
#pragma unroll
        for (int it = 0; it < 2; ++it) {
            int i = tid + it * 256;
            int r = i >> 2, kb = i & 3;
            *(bf16x8*)&As[r][kb * 8] = *(const bf16x8*)&A[(size_t)(row0 + r) * K + kk + kb * 8];
        }
        {
            int r = tid >> 2, kb = tid & 3;
            *(bf16x8*)&Bs[r][kb * 8] = *(const bf16x8*)&Bt[(size_t)(col0 + r) * K + kk + kb * 8];
        }
        __syncthreads();
        int koff = (l >> 4) * 8;
        bf16x8 af[4], bf[2];
#pragma unroll
        for (int m = 0; m < 4; ++m) af[m] = *(bf16x8*)&As[wm + m * 16 + (l & 15)][koff];
#pragma unroll
        for (int n = 0; n < 2; ++n) bf[n] = *(bf16x8*)&Bs[wn + n * 16 + (l & 15)][koff];
#pragma unroll
        for (int m = 0; m < 4; ++m)
#pragma unroll
            for (int n = 0; n < 2; ++n)
                acc[m][n] = __builtin_amdgcn_mfma_f32_16x16x32_bf16(af[m], bf[n], acc[m][n], 0, 0, 0);
    }
    int cg = l & 15, rg = (l >> 4) * 4;
#pragma unroll
    for (int m = 0; m < 4; ++m)
#pragma unroll
        for (int n = 0; n < 2; ++n)
#pragma unroll
            for (int r = 0; r < 4; ++r) {
                int grow = row0 + wm + m * 16 + rg + r;
                int gcol = col0 + wn + n * 16 + cg;
                if (RESID) {
                    ((float*)Cb)[(size_t)grow * N + gcol] += acc[m][n][r];
                } else {
                    ((u16*)Cb)[(size_t)grow * N + gcol] = f2bf(acc[m][n][r]);
                }
            }
}

// ---------------- RoPE apply on fused qkv bf16 (q + k) ----------------
__global__ void rope_k(u16* __restrict__ qkv, const float* __restrict__ ct,
                       const float* __restrict__ st) {
    int i = blockIdx.x * 256 + threadIdx.x;
    if (i >= S_ * NH_ * 32) return;
    int j = i & 31;
    int hh = (i >> 5) & 7;
    int s = i >> 8;
    int base = s * 1536 + hh * HD_ + j;
    float c = ct[s * HD_ + j], sn = st[s * HD_ + j];
    float q0 = bf2f(qkv[base]), q1 = bf2f(qkv[base + 32]);
    qkv[base] = f2bf(q0 * c - q1 * sn);
    qkv[base + 32] = f2bf(q1 * c + q0 * sn);
    float k0 = bf2f(qkv[base + 512]), k1 = bf2f(qkv[base + 512 + 32]);
    qkv[base + 512] = f2bf(k0 * c - k1 * sn);
    qkv[base + 512 + 32] = f2bf(k1 * c + k0 * sn);
}

// ---------------- Attention v3: MFMA flash, swapped operands ----------------
// Block = (head, 64 rows), 4 waves x 16 rows. Swapped QK^T (lane owns one
// q-row -> softmax = in-reg + 2 shfl). P via per-wave LDS. Swapped PV.
__global__ __launch_bounds__(256) void attn3_k(const u16* __restrict__ qkv,
                                               u16* __restrict__ og) {
    __shared__ u16 Kl[64 * 64];      // [key][dim], XOR-swizzled, 8KB
    __shared__ u16 Vt[64 * 64];      // [dim][key], XOR-swizzled, 8KB
    __shared__ u16 Pl[4][16 * 64];   // per-wave P [qrow][key], swizzled, 8KB
    int tid = threadIdx.x;
    int lane = tid & 63, w = tid >> 6;
    int g = lane >> 4, lq = lane & 15;
    int bid = blockIdx.x;
    int head = bid & 7;
    int grp = 63 - (bid >> 3);       // longest horizon first
    int r0 = grp << 6;
    int nk = ((r0 >> 8) + 1) << 8;
    // Q B-fragments (col=qrow=lq, k=dims 8g+j and 32+8g+j)
    const u16* qp = qkv + (size_t)(r0 + w * 16 + lq) * 1536 + head * 64;
    bf16x8 qf0 = *(const bf16x8*)&qp[8 * g];
    bf16x8 qf1 = *(const bf16x8*)&qp[32 + 8 * g];
    f32x4 O[4] = {};
    float m = -3.0e38f, l = 0.0f;
    char* Pw = (char*)Pl[w];
    int swz = (lq & 7) << 4;

    for (int t0 = 0; t0 < nk; t0 += 64) {
        __syncthreads();
        // stage K [key][dim^swz]
#pragma unroll
        for (int i = 0; i < 2; ++i) {
            int it = tid + i * 256;
            int key = it >> 3, dc = it & 7;
            bf16x8 kv = *(const bf16x8*)&qkv[(size_t)(t0 + key) * 1536 + 512 + head * 64 + dc * 8];
            *(bf16x8*)((char*)Kl + key * 128 + ((dc * 16) ^ ((key & 7) << 4))) = kv;
        }
        // stage V^T [dim][key^swz] via register-packed u32 pairs
        {
            int a = tid & 31, b = tid >> 5;
            const u16* vp = &qkv[(size_t)(t0 + 2 * a) * 1536 + 1024 + head * 64 + b * 8];
            bf16x8 v0 = *(const bf16x8*)vp;
            bf16x8 v1 = *(const bf16x8*)(vp + 1536);
#pragma unroll
            for (int j = 0; j < 8; ++j) {
                int d = b * 8 + j;
                unsigned pk = (unsigned)(unsigned short)v0[j] | ((unsigned)(unsigned short)v1[j] << 16);
                *(unsigned*)((char*)Vt + d * 128 + ((4 * a) ^ ((d & 7) << 4))) = pk;
            }
        }
        __syncthreads();
        // swapped QK^T: sc[f] holds D[key=16f+4g+r][qrow=lq]
        f32x4 sc[4] = {};
#pragma unroll
        for (int f = 0; f < 4; ++f) {
            int key = 16 * f + lq;
            int ksw = (key & 7) << 4;
            bf16x8 a0 = *(bf16x8*)((char*)Kl + key * 128 + ((16 * g) ^ ksw));
            bf16x8 a1 = *(bf16x8*)((char*)Kl + key * 128 + ((64 + 16 * g) ^ ksw));
            sc[f] = __builtin_amdgcn_mfma_f32_16x16x32_bf16(a0, qf0, sc[f], 0, 0, 0);
            sc[f] = __builtin_amdgcn_mfma_f32_16x16x32_bf16(a1, qf1, sc[f], 0, 0, 0);
        }
        // online softmax: lane owns q-row lq with keys 16f+4g+r
        float mx = -3.0e38f;
#pragma unroll
        for (int f = 0; f < 4; ++f)
#pragma unroll
            for (int r = 0; r < 4; ++r) {
                sc[f][r] *= 0.125f;
                mx = fmaxf(mx, sc[f][r]);
            }
        mx = fmaxf(mx, __shfl_xor(mx, 16));
        mx = fmaxf(mx, __shfl_xor(mx, 32));
        float mn = fmaxf(m, mx);
        float corr = __expf(m - mn);
        m = mn;
        float sum = 0.0f;
#pragma unroll
        for (int f = 0; f < 4; ++f)
#pragma unroll
            for (int pp = 0; pp < 2; ++pp) {
                float p0 = __expf(sc[f][2 * pp] - mn);
                float p1 = __expf(sc[f][2 * pp + 1] - mn);
                sum += p0 + p1;
                unsigned pk = (unsigned)f2bf(p0) | ((unsigned)f2bf(p1) << 16);
                *(unsigned*)(Pw + lq * 128 + ((32 * f + 8 * g + 4 * pp) ^ swz)) = pk;
            }
        sum += __shfl_xor(sum, 16);
        sum += __shfl_xor(sum, 32);
        l = l * corr + sum;
#pragma unroll
        for (int f = 0; f < 4; ++f) {
            O[f][0] *= corr; O[f][1] *= corr; O[f][2] *= corr; O[f][3] *= corr;
        }
        // swapped PV: O[f] = D[dim=16f+4g+r][qrow=lq]
#pragma unroll
        for (int kk = 0; kk < 2; ++kk) {
            bf16x8 pb = *(bf16x8*)(Pw + lq * 128 + ((64 * kk + 16 * g) ^ swz));
#pragma unroll
            for (int f = 0; f < 4; ++f) {
                int d = 16 * f + lq;
                bf16x8 av = *(bf16x8*)((char*)Vt + d * 128 + ((64 * kk + 16 * g) ^ ((d & 7) << 4)));
                O[f] = __builtin_amdgcn_mfma_f32_16x16x32_bf16(av, pb, O[f], 0, 0, 0);
            }
        }
    }
    float inv = 1.0f / l;
    int srow = r0 + w * 16 + lq;
#pragma unroll
    for (int f = 0; f < 4; ++f)
#pragma unroll
        for (int r = 0; r < 4; ++r)
            og[(size_t)srow * D_ + head * 64 + 16 * f + 4 * g + r] = f2bf(O[f][r] * inv);
}

// ---------------- SiLU(g)*u from fused gu bf16 ----------------
__global__ void silumul_k(const u16* __restrict__ gu, u16* __restrict__ gs) {
    int i = blockIdx.x * 256 + threadIdx.x;
    int s = i >> 11, f = i & 2047;
    float x = bf2f(gu[(size_t)s * 4096 + f]);
    float u = bf2f(gu[(size_t)s * 4096 + 2048 + f]);
    gs[i] = f2bf(x / (1.0f + __expf(-x)) * u);
}

// ---------------- Decoder (bf16 a, fp32 out) ----------------
__global__ void decode_k(const u16* __restrict__ a, const float* __restrict__ W,
                         const float* __restrict__ b, float* __restrict__ out) {
    int i = blockIdx.x * 256 + threadIdx.x;
    if (i >= S_ * C_) return;
    int s = i / C_, c = i - s * C_;
    float acc = b[c];
    for (int d = 0; d < D_; ++d) acc = fmaf(bf2f(a[s * D_ + d]), W[d * C_ + c], acc);
    out[i] = acc;
}

extern "C" void kernel_launch(void* const* d_in, const int* in_sizes, int n_in,
                              void* d_out, int out_size, void* d_ws, size_t ws_size,
                              hipStream_t stream) {
    const float* x = (const float*)d_in[0];
    const float* W_enc = (const float*)d_in[1];
    const float* b_enc = (const float*)d_in[2];
    const float* Wq = (const float*)d_in[3];
    const float* Wk = (const float*)d_in[4];
    const float* Wv = (const float*)d_in[5];
    const float* Wo = (const float*)d_in[6];
    const float* Wg = (const float*)d_in[7];
    const float* Wu = (const float*)d_in[8];
    const float* Wd = (const float*)d_in[9];
    const float* ln1 = (const float*)d_in[10];
    const float* ln2 = (const float*)d_in[11];
    const float* ln_f = (const float*)d_in[12];
    const float* W_dec = (const float*)d_in[13];
    const float* b_dec = (const float*)d_in[14];
    float* out = (float*)d_out;

    char* p = (char*)d_ws;
    float* h = (float*)p;          p += (size_t)S_ * D_ * 4;
    float* ct = (float*)p;         p += (size_t)S_ * HD_ * 4;
    float* st = (float*)p;         p += (size_t)S_ * HD_ * 4;
    u16* a_bf = (u16*)p;           p += (size_t)S_ * D_ * 2;
    u16* qkv = (u16*)p;            p += (size_t)S_ * 1536 * 2;
    u16* ob = (u16*)p;             p += (size_t)S_ * D_ * 2;
    u16* gu = (u16*)p;             p += (size_t)S_ * 4096 * 2;
    u16* gs = (u16*)p;             p += (size_t)S_ * F_ * 2;
    u16* Wqkv_t = (u16*)p;         p += (size_t)L_ * 1536 * 512 * 2;
    u16* Wo_t = (u16*)p;           p += (size_t)L_ * 512 * 512 * 2;
    u16* Wgu_t = (u16*)p;          p += (size_t)L_ * 4096 * 512 * 2;
    u16* Wd_t = (u16*)p;           p += (size_t)L_ * 512 * 2048 * 2;

    rope_table_k<<<S_ * HD_ / 256, 256, 0, stream>>>(ct, st);
    encoder_k<<<S_ * D_ / 256, 256, 0, stream>>>(x, W_enc, b_enc, h);

    dim3 c512(16, 16, L_);
    conv_t_k<<<c512, 256, 0, stream>>>(Wq, Wqkv_t, 512, 512, 512L * 512, 1536L * 512, 0);
    conv_t_k<<<c512, 256, 0, stream>>>(Wk, Wqkv_t, 512, 512, 512L * 512, 1536L * 512, 512L * 512);
    conv_t_k<<<c512, 256, 0, stream>>>(Wv, Wqkv_t, 512, 512, 512L * 512, 1536L * 512, 1024L * 512);
    conv_t_k<<<c512, 256, 0, stream>>>(Wo, Wo_t, 512, 512, 512L * 512, 512L * 512, 0);
    dim3 cgu(64, 16, L_);
    conv_t_k<<<cgu, 256, 0, stream>>>(Wg, Wgu_t, 512, 2048, 512L * 2048, 4096L * 512, 0);
    conv_t_k<<<cgu, 256, 0, stream>>>(Wu, Wgu_t, 512, 2048, 512L * 2048, 4096L * 512, 2048L * 512);
    dim3 cwd(16, 64, L_);
    conv_t_k<<<cwd, 256, 0, stream>>>(Wd, Wd_t, 2048, 512, 2048L * 512, 512L * 2048, 0);

    dim3 gqkv(1536 / 64, S_ / 128);
    dim3 ggu(4096 / 64, S_ / 128);
    dim3 g512(512 / 64, S_ / 128);
    for (int l = 0; l < L_; ++l) {
        rmsnorm_k<<<S_, 256, 0, stream>>>(h, ln1 + l * D_, a_bf);
        mm_k<0><<<gqkv, 256, 0, stream>>>(a_bf, Wqkv_t + (size_t)l * 1536 * 512, qkv, S_, 1536, 512);
        rope_k<<<S_ * NH_ * 32 / 256, 256, 0, stream>>>(qkv, ct, st);
        attn3_k<<<(S_ / 64) * NH_, 256, 0, stream>>>(qkv, ob);
        mm_k<1><<<g512, 256, 0, stream>>>(ob, Wo_t + (size_t)l * 512 * 512, h, S_, 512, 512);
        rmsnorm_k<<<S_, 256, 0, stream>>>(h, ln2 + l * D_, a_bf);
        mm_k<0><<<ggu, 256, 0, stream>>>(a_bf, Wgu_t + (size_t)l * 4096 * 512, gu, S_, 4096, 512);
        silumul_k<<<S_ * F_ / 256, 256, 0, stream>>>(gu, gs);
        mm_k<1><<<g512, 256, 0, stream>>>(gs, Wd_t + (size_t)l * 512 * 2048, h, S_, 512, 2048);
    }
    rmsnorm_k<<<S_, 256, 0, stream>>>(h, ln_f, a_bf);
    decode_k<<<(S_ * C_ + 255) / 256, 256, 0, stream>>>(a_bf, W_dec, b_dec, out);
}